// Round 4
// baseline (1286.692 us; speedup 1.0000x reference)
//
#include <hip/hip_runtime.h>

// VQ-VAE vector quantization, MI355X gfx950.
// B=16, C=64, H=W=64 -> N=65536 pixels; K=1024 codes, dim 64.
// NUMERICS (DO NOT CHANGE — r7 passed absmax 0.0 with exactly this):
//   nz/ne: numpy pairwise sum, 8-accumulator unroll, products rounded
//          separately (no fma contraction);
//   dot:   single ascending fp32 fma chain per (pixel,code);
//   d = fl( fl(nz - fl(2*dot)) + ne ); strict-< ascending-k tie-break.
//   ~135 pixels are decided by quantized ties.
//
// Perf history:
//   r7  PXT=1 LDS-broadcast                 161 µs
//   r8  uniform vector global loads         185 µs (vector-L1 path worse)
//   r9  PXT=2 @ (256,2)                     137 µs argmin, VALUBusy 65%
//   r12 PXT=4 @ (256,1)                     242 µs — 1 wave/SIMD can't hide
//       lgkmcnt latency; zr spilled. TLP does the hiding, not ILP.
//   r13 PXT=2 @ (256,3)                     137 µs argmin, VALUBusy 65%,
//       occ 25% — occupancy-invariant 65% ceiling.
// Model (fits r9+r13 exactly): LDS pipe is CU-shared; broadcast ds_read_b128
// return = 64 lanes x 16B = 1KB / 256B/clk >= 4 cyc (+~2 issue) = c~6.
// Each b128 feeds 4R FMAs (R = px/thread). VALUBusy ceiling = 2R/c.
// R=2, c=6 -> 0.67 == measured 65%. Lever = R.
// r14: R=3 @ (256,2) with register diet: #pragma unroll 4 on the j-loop
// bounds in-flight b128 staging to 8 (32 dest regs) vs r9's full-unroll 128.
// Target ~245 regs <= 256/wave cap. Grid 86x8; block 85 is a block-uniform
// tail (p1,p2 >= N_PIX for all its threads).
// Fused prep + fused loss (r12/r13 bit-validated) kept verbatim.
#define N_PIX   65536
#define CDIM    64
#define KCODES  1024
#define HWSZ    4096          // H*W
#define KCHUNK  128           // codes per argmin block
#define NCHUNK  8             // KCODES / KCHUNK
#define TPB     256
#define PXT     3             // pixels per thread
#define GRIDX   ((N_PIX + TPB*PXT - 1) / (TPB*PXT))   // 86

// workspace layout (float-element offsets)
#define OFF_CTR  0            // 1 u32: finalize done-counter
#define OFF_MIN  1024         // 65536*8 f32: per-chunk min score
#define OFF_IDX  525312       // 65536*8 i32: per-chunk argmin
#define OFF_LOSS 1049600      // 1 f32: SSE accumulator

// output layout (float-element offsets): z_q | indices | loss
#define OUT_IDX  (N_PIX * CDIM)         // 4194304
#define OUT_LOSS (OUT_IDX + N_PIX)      // 4259840

// exact numpy pairwise ||.||^2 for pixel registers — EXACT r9-verified form.
__device__ __forceinline__ float np_nz(const float* zr) {
    float r0 = zr[0]*zr[0], r1 = zr[1]*zr[1], r2 = zr[2]*zr[2], r3 = zr[3]*zr[3];
    float r4 = zr[4]*zr[4], r5 = zr[5]*zr[5], r6 = zr[6]*zr[6], r7 = zr[7]*zr[7];
#pragma unroll
    for (int i = 8; i < CDIM; i += 8) {
        r0 = r0 + zr[i+0]*zr[i+0]; r1 = r1 + zr[i+1]*zr[i+1];
        r2 = r2 + zr[i+2]*zr[i+2]; r3 = r3 + zr[i+3]*zr[i+3];
        r4 = r4 + zr[i+4]*zr[i+4]; r5 = r5 + zr[i+5]*zr[i+5];
        r6 = r6 + zr[i+6]*zr[i+6]; r7 = r7 + zr[i+7]*zr[i+7];
    }
    return ((r0 + r1) + (r2 + r3)) + ((r4 + r5) + (r6 + r7));
}

// ---------------- Kernel A: split-K argmin, 3 px/thread, LDS broadcast ------
// grid = (GRIDX, NCHUNK); block = TPB. Also computes ||e||^2 per chunk
// (fused prep, validated) and zeroes the loss slot + done counter.
__global__ __launch_bounds__(TPB, 2) void vq_argmin(const float* __restrict__ z,
                                                    const float* __restrict__ emb,
                                                    float* __restrict__ cmin,
                                                    int* __restrict__ cidx,
                                                    float* __restrict__ ws) {
#pragma clang fp contract(off)
    __shared__ float se[KCHUNK * CDIM];   // 32 KB
    __shared__ float sn[KCHUNK];

    const int chunk = blockIdx.y;
    const int k0 = chunk * KCHUNK;

    if ((blockIdx.x | blockIdx.y) == 0 && threadIdx.x == 0) {
        ws[OFF_LOSS] = 0.0f;                       // stream-ordered before finalize
        ((unsigned*)ws)[OFF_CTR] = 0u;             // graph-replay / re-poison safe
    }

    // stage this chunk's embedding rows (coalesced float4)
    const float4* esrc = (const float4*)(emb + (size_t)k0 * CDIM);
    float4* edst = (float4*)se;
    for (int i = threadIdx.x; i < KCHUNK * CDIM / 4; i += TPB) edst[i] = esrc[i];
    __syncthreads();
    // fused prep: ||e_k||^2 from the bit-exact staged copy (validated).
    if (threadIdx.x < KCHUNK) {
        const float* e = se + threadIdx.x * CDIM;
        float r0 = e[0]*e[0], r1 = e[1]*e[1], r2 = e[2]*e[2], r3 = e[3]*e[3];
        float r4 = e[4]*e[4], r5 = e[5]*e[5], r6 = e[6]*e[6], r7 = e[7]*e[7];
#pragma unroll
        for (int i = 8; i < CDIM; i += 8) {
            r0 = r0 + e[i+0]*e[i+0]; r1 = r1 + e[i+1]*e[i+1];
            r2 = r2 + e[i+2]*e[i+2]; r3 = r3 + e[i+3]*e[i+3];
            r4 = r4 + e[i+4]*e[i+4]; r5 = r5 + e[i+5]*e[i+5];
            r6 = r6 + e[i+6]*e[i+6]; r7 = r7 + e[i+7]*e[i+7];
        }
        sn[threadIdx.x] = ((r0 + r1) + (r2 + r3)) + ((r4 + r5) + (r6 + r7));
    }
    __syncthreads();

    // three pixels per thread, lane-coalesced. Only block 85 has q1/q2 false,
    // and there they are false for EVERY thread (block-uniform, no divergence).
    const int p0 = blockIdx.x * (TPB * PXT) + threadIdx.x;   // always < N_PIX
    const int p1 = p0 + TPB;
    const int p2 = p1 + TPB;
    const bool q1 = (p1 < N_PIX);
    const bool q2 = (p2 < N_PIX);

    float zr0[CDIM], zr1[CDIM], zr2[CDIM];
    {
        const int b0 = p0 >> 12, hw0 = p0 & (HWSZ - 1);
        const float* zp0 = z + ((size_t)(b0 * CDIM) << 12) + hw0;
#pragma unroll
        for (int c = 0; c < CDIM; ++c) zr0[c] = zp0[(size_t)c << 12];
    }
    if (q1) {
        const int b1 = p1 >> 12, hw1 = p1 & (HWSZ - 1);
        const float* zp1 = z + ((size_t)(b1 * CDIM) << 12) + hw1;
#pragma unroll
        for (int c = 0; c < CDIM; ++c) zr1[c] = zp1[(size_t)c << 12];
    } else {
#pragma unroll
        for (int c = 0; c < CDIM; ++c) zr1[c] = 0.0f;
    }
    if (q2) {
        const int b2 = p2 >> 12, hw2 = p2 & (HWSZ - 1);
        const float* zp2 = z + ((size_t)(b2 * CDIM) << 12) + hw2;
#pragma unroll
        for (int c = 0; c < CDIM; ++c) zr2[c] = zp2[(size_t)c << 12];
    } else {
#pragma unroll
        for (int c = 0; c < CDIM; ++c) zr2[c] = 0.0f;
    }
    const float nz0 = np_nz(zr0);
    const float nz1 = np_nz(zr1);
    const float nz2 = np_nz(zr2);

    float best0 = 3.4e38f, best1 = 3.4e38f, best2 = 3.4e38f;
    int   bi0   = k0,      bi1   = k0,      bi2   = k0;
    for (int kk = 0; kk < KCHUNK; kk += 2) {
        const float4* e0 = (const float4*)(se + kk * CDIM);
        const float4* e1 = e0 + (CDIM / 4);
        float a00 = 0.f, a01 = 0.f, a10 = 0.f, a11 = 0.f, a20 = 0.f, a21 = 0.f;
        // unroll 4 (not 16): bounds in-flight b128 staging to 8 reads
        // (32 dest VGPRs) so zr0..zr2 (192 regs) fit under the 256/wave cap.
#pragma unroll 4
        for (int j = 0; j < 16; ++j) {
            float4 v0 = e0[j];                 // uniform addr -> LDS broadcast
            float4 v1 = e1[j];
            a00 = fmaf(zr0[4*j+0], v0.x, a00);
            a00 = fmaf(zr0[4*j+1], v0.y, a00);
            a00 = fmaf(zr0[4*j+2], v0.z, a00);
            a00 = fmaf(zr0[4*j+3], v0.w, a00);
            a01 = fmaf(zr0[4*j+0], v1.x, a01);
            a01 = fmaf(zr0[4*j+1], v1.y, a01);
            a01 = fmaf(zr0[4*j+2], v1.z, a01);
            a01 = fmaf(zr0[4*j+3], v1.w, a01);
            a10 = fmaf(zr1[4*j+0], v0.x, a10);
            a10 = fmaf(zr1[4*j+1], v0.y, a10);
            a10 = fmaf(zr1[4*j+2], v0.z, a10);
            a10 = fmaf(zr1[4*j+3], v0.w, a10);
            a11 = fmaf(zr1[4*j+0], v1.x, a11);
            a11 = fmaf(zr1[4*j+1], v1.y, a11);
            a11 = fmaf(zr1[4*j+2], v1.z, a11);
            a11 = fmaf(zr1[4*j+3], v1.w, a11);
            a20 = fmaf(zr2[4*j+0], v0.x, a20);
            a20 = fmaf(zr2[4*j+1], v0.y, a20);
            a20 = fmaf(zr2[4*j+2], v0.z, a20);
            a20 = fmaf(zr2[4*j+3], v0.w, a20);
            a21 = fmaf(zr2[4*j+0], v1.x, a21);
            a21 = fmaf(zr2[4*j+1], v1.y, a21);
            a21 = fmaf(zr2[4*j+2], v1.z, a21);
            a21 = fmaf(zr2[4*j+3], v1.w, a21);
        }
        float d00 = (nz0 - 2.0f * a00) + sn[kk];
        float d01 = (nz0 - 2.0f * a01) + sn[kk + 1];
        float d10 = (nz1 - 2.0f * a10) + sn[kk];
        float d11 = (nz1 - 2.0f * a11) + sn[kk + 1];
        float d20 = (nz2 - 2.0f * a20) + sn[kk];
        float d21 = (nz2 - 2.0f * a21) + sn[kk + 1];
        if (d00 < best0) { best0 = d00; bi0 = k0 + kk; }
        if (d01 < best0) { best0 = d01; bi0 = k0 + kk + 1; }
        if (d10 < best1) { best1 = d10; bi1 = k0 + kk; }
        if (d11 < best1) { best1 = d11; bi1 = k0 + kk + 1; }
        if (d20 < best2) { best2 = d20; bi2 = k0 + kk; }
        if (d21 < best2) { best2 = d21; bi2 = k0 + kk + 1; }
    }
    cmin[(p0 << 3) + chunk] = best0;
    cidx[(p0 << 3) + chunk] = bi0;
    if (q1) { cmin[(p1 << 3) + chunk] = best1; cidx[(p1 << 3) + chunk] = bi1; }
    if (q2) { cmin[(p2 << 3) + chunk] = best2; cidx[(p2 << 3) + chunk] = bi2; }
}

// ---------------- Kernel B: reduce chunks, gather z_q, loss + emit ----------
__global__ __launch_bounds__(TPB) void vq_finalize(const float* __restrict__ z,
                                                   const float* __restrict__ emb,
                                                   const float* __restrict__ cmin,
                                                   const int* __restrict__ cidx,
                                                   float* __restrict__ out,
                                                   float* __restrict__ ws) {
    const int p = blockIdx.x * TPB + threadIdx.x;

    // ascending-chunk strict < keeps the earliest (lowest-k) minimum
    float best = cmin[p << 3];
    int   bi   = cidx[p << 3];
#pragma unroll
    for (int ch = 1; ch < NCHUNK; ++ch) {
        float m = cmin[(p << 3) + ch];
        if (m < best) { best = m; bi = cidx[(p << 3) + ch]; }
    }

    out[OUT_IDX + p] = (float)bi;       // indices output (fp32)

    const float* ev = emb + bi * CDIM;
    const int b  = p >> 12;
    const int hw = p & (HWSZ - 1);
    const float* zp = z + ((size_t)(b * CDIM) << 12) + hw;
    float* zq = out + ((size_t)(b * CDIM) << 12) + hw;

    float ls = 0.0f;
#pragma unroll
    for (int c = 0; c < CDIM; ++c) {
        float e = ev[c];                    // gather: rows hit L1/L2 (256KB table)
        float zv = zp[(size_t)c << 12];
        float d = e - zv;
        ls = fmaf(d, d, ls);
        zq[(size_t)c << 12] = e;            // fp32 z_q, coalesced strided store
    }

    // block reduction -> one atomic per block; last block scales + emits loss
#pragma unroll
    for (int off = 32; off > 0; off >>= 1) ls += __shfl_down(ls, off);
    __shared__ float wsum[TPB / 64];
    if ((threadIdx.x & 63) == 0) wsum[threadIdx.x >> 6] = ls;
    __syncthreads();
    if (threadIdx.x == 0) {
        float s = wsum[0] + wsum[1] + wsum[2] + wsum[3];
        float* loss_acc = ws + OFF_LOSS;
        atomicAdd(loss_acc, s);
        __threadfence();                               // add visible before count
        unsigned* ctr = (unsigned*)ws + OFF_CTR;
        unsigned old = atomicAdd(ctr, 1u);
        if (old == (unsigned)(gridDim.x - 1)) {        // last block: all adds done
            __threadfence();
            float total = atomicAdd(loss_acc, 0.0f);   // coherent L2 read
            // vq_loss + beta*commitment = (1+0.25) * SSE / numel(z)
            out[OUT_LOSS] = total * (1.25f / (float)(N_PIX * CDIM));
        }
    }
}

extern "C" void kernel_launch(void* const* d_in, const int* in_sizes, int n_in,
                              void* d_out, int out_size, void* d_ws, size_t ws_size,
                              hipStream_t stream) {
    const float* z   = (const float*)d_in[0];
    const float* emb = (const float*)d_in[1];
    float* ws   = (float*)d_ws;
    float* out  = (float*)d_out;
    float* cmin = ws + OFF_MIN;
    int*   cidx = (int*)(ws + OFF_IDX);

    vq_argmin<<<dim3(GRIDX, NCHUNK), dim3(TPB), 0, stream>>>(z, emb, cmin, cidx, ws);
    vq_finalize<<<dim3(N_PIX / TPB), dim3(TPB), 0, stream>>>(z, emb, cmin, cidx, out, ws);
}

// Round 5
// 199.740 us; speedup vs baseline: 6.4418x; 6.4418x over previous
//
#include <hip/hip_runtime.h>

// VQ-VAE vector quantization, MI355X gfx950.
// B=16, C=64, H=W=64 -> N=65536 pixels; K=1024 codes, dim 64.
// NUMERICS (DO NOT CHANGE — r7 passed absmax 0.0 with exactly this):
//   nz/ne: numpy pairwise sum, 8-accumulator unroll, products rounded
//          separately (no fma contraction);
//   dot:   single ascending fp32 fma chain per (pixel,code);
//   d = fl( fl(nz - fl(2*dot)) + ne ); strict-< ascending-k tie-break.
//   ~135 pixels are decided by quantized ties.
//
// Perf history:
//   r7  PXT=1 LDS-broadcast                 161 µs
//   r8  uniform VECTOR global loads         185 µs (vector-L1 return path)
//   r9  PXT=2 @ (256,2)                     137 µs argmin, VALUBusy 65%
//   r12 PXT=4 @ (256,1)                     242 µs — TLP hides latency, not ILP
//   r13 PXT=2 @ (256,3)                     137 µs, VALUBusy 65% — occupancy-
//       invariant ceiling. Model: broadcast ds_read_b128 costs c~6 cyc on the
//       CU-shared LDS pipe; ceiling = 2R/c = 0.67 at R=2. Confirmed twice.
//   r14 PXT=3 reg-diet                      1244 µs — zr spilled to scratch
//       (FETCH 3.8 GB). R=2 is the register-feasible max. R-lever DEAD.
// r15: attack c instead — move e operands to the SCALAR pipe. e rows are
// wave-uniform; v_fma_f32 takes one SGPR operand (zr=VGPR, e=SGPR, acc=VGPR).
// Inline-asm s_load_dwordx16 streams rows into SGPRs (SMEM pipe, not LDS,
// not vector L1 — r8 tested the VECTOR uniform path, never the scalar one).
// Inner loop has ZERO LDS instructions. Per code-pair: 2 phases x
// {4x s_load_dwordx16 + wait, 128 FMA in 4 indep 32-link chains}.
// No LDS in argmin at all -> (256,3) occupancy (r13-proven no-spill shape)
// covers the ~200cy SMEM latency. ne via restored r7-verbatim vq_prep
// (same ws bits as every validated round); 4-dispatch r7 loss path restored
// (no spare ws slot for the done-counter trick).
#define N_PIX   65536
#define CDIM    64
#define KCODES  1024
#define HWSZ    4096          // H*W
#define KCHUNK  128           // codes per argmin block (K-split only; no LDS)
#define NCHUNK  8             // KCODES / KCHUNK
#define TPB     256
#define PXT     2             // pixels per thread; 128*256*2 == N_PIX exactly
#define GRIDX   (N_PIX / (TPB * PXT))   // 128

// workspace layout (float-element offsets) — original r7 layout
#define OFF_NE   0            // 1024   f32: ||e_k||^2 (numpy pairwise)
#define OFF_MIN  1024         // 65536*8 f32: per-chunk min score
#define OFF_IDX  525312       // 65536*8 i32: per-chunk argmin
#define OFF_LOSS 1049600      // 1 f32: SSE accumulator

// output layout (float-element offsets): z_q | indices | loss
#define OUT_IDX  (N_PIX * CDIM)         // 4194304
#define OUT_LOSS (OUT_IDX + N_PIX)      // 4259840

typedef __attribute__((ext_vector_type(16))) float f32x16;
typedef __attribute__((ext_vector_type(2)))  float f32x2;

// ---------------- Kernel A: ||e_k||^2 (numpy order), zero loss --------------
// r7-verbatim (validated absmax 0.0).
__global__ void vq_prep(const float* __restrict__ emb, float* __restrict__ ws) {
#pragma clang fp contract(off)
    int k = blockIdx.x * blockDim.x + threadIdx.x;   // 1024 threads
    if (k == 0) ws[OFF_LOSS] = 0.0f;
    if (k >= KCODES) return;
    const float* e = emb + k * CDIM;
    float r0 = e[0]*e[0], r1 = e[1]*e[1], r2 = e[2]*e[2], r3 = e[3]*e[3];
    float r4 = e[4]*e[4], r5 = e[5]*e[5], r6 = e[6]*e[6], r7 = e[7]*e[7];
    for (int i = 8; i < CDIM; i += 8) {
        r0 = r0 + e[i+0]*e[i+0]; r1 = r1 + e[i+1]*e[i+1];
        r2 = r2 + e[i+2]*e[i+2]; r3 = r3 + e[i+3]*e[i+3];
        r4 = r4 + e[i+4]*e[i+4]; r5 = r5 + e[i+5]*e[i+5];
        r6 = r6 + e[i+6]*e[i+6]; r7 = r7 + e[i+7]*e[i+7];
    }
    ws[OFF_NE + k] = ((r0 + r1) + (r2 + r3)) + ((r4 + r5) + (r6 + r7));
}

// exact numpy pairwise ||.||^2 for pixel registers — EXACT r9-verified form.
__device__ __forceinline__ float np_nz(const float* zr) {
    float r0 = zr[0]*zr[0], r1 = zr[1]*zr[1], r2 = zr[2]*zr[2], r3 = zr[3]*zr[3];
    float r4 = zr[4]*zr[4], r5 = zr[5]*zr[5], r6 = zr[6]*zr[6], r7 = zr[7]*zr[7];
#pragma unroll
    for (int i = 8; i < CDIM; i += 8) {
        r0 = r0 + zr[i+0]*zr[i+0]; r1 = r1 + zr[i+1]*zr[i+1];
        r2 = r2 + zr[i+2]*zr[i+2]; r3 = r3 + zr[i+3]*zr[i+3];
        r4 = r4 + zr[i+4]*zr[i+4]; r5 = r5 + zr[i+5]*zr[i+5];
        r6 = r6 + zr[i+6]*zr[i+6]; r7 = r7 + zr[i+7]*zr[i+7];
    }
    return ((r0 + r1) + (r2 + r3)) + ((r4 + r5) + (r6 + r7));
}

// ---------------- Kernel B: split-K argmin, SGPR-streamed codes -------------
// grid = (GRIDX, NCHUNK); block = TPB. No LDS.
__global__ __launch_bounds__(TPB, 3) void vq_argmin(const float* __restrict__ z,
                                                    const float* __restrict__ ws,
                                                    const float* __restrict__ emb,
                                                    float* __restrict__ cmin,
                                                    int* __restrict__ cidx) {
#pragma clang fp contract(off)
    const int chunk = blockIdx.y;
    const int k0 = chunk * KCHUNK;

    // two pixels per thread, lane-coalesced; no tail (128*256*2 == N_PIX)
    const int p0 = blockIdx.x * (TPB * PXT) + threadIdx.x;
    const int p1 = p0 + TPB;

    float zr0[CDIM], zr1[CDIM];
    {
        const int b0  = p0 >> 12, hw0 = p0 & (HWSZ - 1);
        const int b1  = p1 >> 12, hw1 = p1 & (HWSZ - 1);
        const float* zp0 = z + ((size_t)(b0 * CDIM) << 12) + hw0;
        const float* zp1 = z + ((size_t)(b1 * CDIM) << 12) + hw1;
#pragma unroll
        for (int c = 0; c < CDIM; ++c) {
            zr0[c] = zp0[(size_t)c << 12];
            zr1[c] = zp1[(size_t)c << 12];
        }
    }
    const float nz0 = np_nz(zr0);
    const float nz1 = np_nz(zr1);

    float best0 = 3.4e38f, best1 = 3.4e38f;
    int   bi0   = k0,      bi1   = k0;

    const float* wsne = ws + OFF_NE + k0;

    for (int kk = 0; kk < KCHUNK; kk += 2) {
        // uniform (scalar) addresses for this code pair
        const float* erow = emb + (size_t)(k0 + kk) * CDIM;   // row kk; kk+1 at +256B
        const float* snp  = wsne + kk;

        float a00 = 0.f, a01 = 0.f, a10 = 0.f, a11 = 0.f;

        // ---- phase A: dims 0..31 of codes kk and kk+1, + ne pair ----
        f32x16 ea0, ea1, eb0, eb1;
        f32x2  snv;
        asm volatile(
            "s_load_dwordx16 %0, %5, 0x0\n\t"
            "s_load_dwordx16 %1, %5, 0x40\n\t"
            "s_load_dwordx16 %2, %5, 0x100\n\t"
            "s_load_dwordx16 %3, %5, 0x140\n\t"
            "s_load_dwordx2  %4, %6, 0x0\n\t"
            "s_waitcnt lgkmcnt(0)"
            : "=s"(ea0), "=s"(ea1), "=s"(eb0), "=s"(eb1), "=s"(snv)
            : "s"(erow), "s"(snp));
#pragma unroll
        for (int j = 0; j < 16; ++j) {
            a00 = fmaf(zr0[j], ea0[j], a00);        // v_fma: VGPR,SGPR,VGPR
            a01 = fmaf(zr0[j], eb0[j], a01);
            a10 = fmaf(zr1[j], ea0[j], a10);
            a11 = fmaf(zr1[j], eb0[j], a11);
        }
#pragma unroll
        for (int j = 0; j < 16; ++j) {
            a00 = fmaf(zr0[16+j], ea1[j], a00);
            a01 = fmaf(zr0[16+j], eb1[j], a01);
            a10 = fmaf(zr1[16+j], ea1[j], a10);
            a11 = fmaf(zr1[16+j], eb1[j], a11);
        }

        // ---- phase B: dims 32..63 of codes kk and kk+1 ----
        f32x16 ec0, ec1, ed0, ed1;
        asm volatile(
            "s_load_dwordx16 %0, %4, 0x80\n\t"
            "s_load_dwordx16 %1, %4, 0xc0\n\t"
            "s_load_dwordx16 %2, %4, 0x180\n\t"
            "s_load_dwordx16 %3, %4, 0x1c0\n\t"
            "s_waitcnt lgkmcnt(0)"
            : "=s"(ec0), "=s"(ec1), "=s"(ed0), "=s"(ed1)
            : "s"(erow));
#pragma unroll
        for (int j = 0; j < 16; ++j) {
            a00 = fmaf(zr0[32+j], ec0[j], a00);
            a01 = fmaf(zr0[32+j], ed0[j], a01);
            a10 = fmaf(zr1[32+j], ec0[j], a10);
            a11 = fmaf(zr1[32+j], ed0[j], a11);
        }
#pragma unroll
        for (int j = 0; j < 16; ++j) {
            a00 = fmaf(zr0[48+j], ec1[j], a00);
            a01 = fmaf(zr0[48+j], ed1[j], a01);
            a10 = fmaf(zr1[48+j], ec1[j], a10);
            a11 = fmaf(zr1[48+j], ed1[j], a11);
        }

        // d and argmin — exact r9 expression shapes and update order
        float d00 = (nz0 - 2.0f * a00) + snv[0];
        float d01 = (nz0 - 2.0f * a01) + snv[1];
        float d10 = (nz1 - 2.0f * a10) + snv[0];
        float d11 = (nz1 - 2.0f * a11) + snv[1];
        if (d00 < best0) { best0 = d00; bi0 = k0 + kk; }
        if (d01 < best0) { best0 = d01; bi0 = k0 + kk + 1; }
        if (d10 < best1) { best1 = d10; bi1 = k0 + kk; }
        if (d11 < best1) { best1 = d11; bi1 = k0 + kk + 1; }
    }
    cmin[(p0 << 3) + chunk] = best0;
    cidx[(p0 << 3) + chunk] = bi0;
    cmin[(p1 << 3) + chunk] = best1;
    cidx[(p1 << 3) + chunk] = bi1;
}

// ---------------- Kernel C: reduce chunks, gather z_q, loss -----------------
__global__ __launch_bounds__(TPB) void vq_finalize(const float* __restrict__ z,
                                                   const float* __restrict__ emb,
                                                   const float* __restrict__ cmin,
                                                   const int* __restrict__ cidx,
                                                   float* __restrict__ out,
                                                   float* __restrict__ loss_acc) {
    const int p = blockIdx.x * TPB + threadIdx.x;

    // ascending-chunk strict < keeps the earliest (lowest-k) minimum
    float best = cmin[p << 3];
    int   bi   = cidx[p << 3];
#pragma unroll
    for (int ch = 1; ch < NCHUNK; ++ch) {
        float m = cmin[(p << 3) + ch];
        if (m < best) { best = m; bi = cidx[(p << 3) + ch]; }
    }

    out[OUT_IDX + p] = (float)bi;       // indices output (fp32)

    const float* ev = emb + bi * CDIM;
    const int b  = p >> 12;
    const int hw = p & (HWSZ - 1);
    const float* zp = z + ((size_t)(b * CDIM) << 12) + hw;
    float* zq = out + ((size_t)(b * CDIM) << 12) + hw;

    float ls = 0.0f;
#pragma unroll
    for (int c = 0; c < CDIM; ++c) {
        float e = ev[c];                    // gather: rows hit L1/L2 (256KB table)
        float zv = zp[(size_t)c << 12];
        float d = e - zv;
        ls = fmaf(d, d, ls);
        zq[(size_t)c << 12] = e;            // fp32 z_q, coalesced strided store
    }

    // block reduction -> one atomic per block
#pragma unroll
    for (int off = 32; off > 0; off >>= 1) ls += __shfl_down(ls, off);
    __shared__ float wsum[TPB / 64];
    if ((threadIdx.x & 63) == 0) wsum[threadIdx.x >> 6] = ls;
    __syncthreads();
    if (threadIdx.x == 0) {
        float s = wsum[0] + wsum[1] + wsum[2] + wsum[3];
        atomicAdd(loss_acc, s);
    }
}

// ---------------- Kernel D: scale + emit loss -------------------------------
__global__ void vq_loss_out(const float* __restrict__ loss_acc, float* __restrict__ out) {
    // vq_loss + beta*commitment = (1+0.25) * SSE / numel(z)
    out[OUT_LOSS] = loss_acc[0] * (1.25f / (float)(N_PIX * CDIM));
}

extern "C" void kernel_launch(void* const* d_in, const int* in_sizes, int n_in,
                              void* d_out, int out_size, void* d_ws, size_t ws_size,
                              hipStream_t stream) {
    const float* z   = (const float*)d_in[0];
    const float* emb = (const float*)d_in[1];
    float* ws   = (float*)d_ws;
    float* out  = (float*)d_out;
    float* cmin = ws + OFF_MIN;
    int*   cidx = (int*)(ws + OFF_IDX);
    float* lossp = ws + OFF_LOSS;

    vq_prep<<<dim3(KCODES / TPB), dim3(TPB), 0, stream>>>(emb, ws);
    vq_argmin<<<dim3(GRIDX, NCHUNK), dim3(TPB), 0, stream>>>(z, ws, emb, cmin, cidx);
    vq_finalize<<<dim3(N_PIX / TPB), dim3(TPB), 0, stream>>>(z, emb, cmin, cidx, out, lossp);
    vq_loss_out<<<1, 1, 0, stream>>>(lossp, out);
}

// Round 6
// 196.267 us; speedup vs baseline: 6.5558x; 1.0177x over previous
//
#include <hip/hip_runtime.h>

// VQ-VAE vector quantization, MI355X gfx950.
// B=16, C=64, H=W=64 -> N=65536 pixels; K=1024 codes, dim 64.
// NUMERICS (DO NOT CHANGE — r7 passed absmax 0.0 with exactly this):
//   nz/ne: numpy pairwise sum, 8-accumulator unroll, products rounded
//          separately (no fma contraction);
//   dot:   single ascending fp32 fma chain per (pixel,code);
//   d = fl( fl(nz - fl(2*dot)) + ne ); strict-< ascending-k tie-break.
//   ~135 pixels are decided by quantized ties.
//
// Perf history:
//   r7  PXT=1 LDS-broadcast                 161 µs
//   r8  uniform VECTOR global loads         185 µs (vector-L1 return path)
//   r9  PXT=2 @ (256,2) LDS-broadcast       137 µs argmin, VALUBusy 65%
//   r12 PXT=4 @ (256,1)                     242 µs — TLP hides latency, not ILP
//   r13 PXT=2 @ (256,3)                     137 µs, VALUBusy 65% — LDS-pipe
//       ceiling 2R/c = 0.67 at R=2, c~6. Occupancy-invariant. Confirmed 2x.
//   r14 PXT=3 reg-diet                      1244 µs — zr scratch-spilled.
//       R=2 is the register-feasible max. R-lever DEAD.
//   r15 SGPR-streamed codes (no LDS)        135 µs argmin, VALUBusy 50%,
//       VALU-busy TIME 89->67 µs (SGPR-operand FMAs are lean) — but the
//       in-loop blocking s_waitcnt lgkmcnt(0) stalls ~250cy/phase.
//       SMEM is out-of-order -> counted lgkmcnt unsafe; 2-deep SGPR
//       buffer (132 regs) > 102-SGPR file. Both pipes half-idle.
// r16: HYBRID — per code pair, code kk via LDS broadcast (r9 chain), code
// kk+1 via SGPR stream (r15 chain). LDS traffic halves -> pipe ceiling 1.33
// (not binding); s_loads issue before the 256-cyc LDS-FMA phase -> wait ~free.
// Ordering by data deps: wait asm is "+s"(ec*) "+v"(a00,a10) so it sits
// between the LDS-phase and SGPR-phase FMAs. Single 64-SGPR buffer fits.
// Fused prep (sn in LDS) + fused loss done-counter (r12/r13/r14-validated).
#define N_PIX   65536
#define CDIM    64
#define KCODES  1024
#define HWSZ    4096          // H*W
#define KCHUNK  128           // codes per argmin block
#define NCHUNK  8             // KCODES / KCHUNK
#define TPB     256
#define PXT     2             // pixels per thread; 128*256*2 == N_PIX exactly
#define GRIDX   (N_PIX / (TPB * PXT))   // 128

// workspace layout (float-element offsets) — fused (r13) layout
#define OFF_CTR  0            // 1 u32: finalize done-counter
#define OFF_MIN  1024         // 65536*8 f32: per-chunk min score
#define OFF_IDX  525312       // 65536*8 i32: per-chunk argmin
#define OFF_LOSS 1049600      // 1 f32: SSE accumulator

// output layout (float-element offsets): z_q | indices | loss
#define OUT_IDX  (N_PIX * CDIM)         // 4194304
#define OUT_LOSS (OUT_IDX + N_PIX)      // 4259840

typedef __attribute__((ext_vector_type(16))) float f32x16;

// exact numpy pairwise ||.||^2 for pixel registers — EXACT r9-verified form.
__device__ __forceinline__ float np_nz(const float* zr) {
    float r0 = zr[0]*zr[0], r1 = zr[1]*zr[1], r2 = zr[2]*zr[2], r3 = zr[3]*zr[3];
    float r4 = zr[4]*zr[4], r5 = zr[5]*zr[5], r6 = zr[6]*zr[6], r7 = zr[7]*zr[7];
#pragma unroll
    for (int i = 8; i < CDIM; i += 8) {
        r0 = r0 + zr[i+0]*zr[i+0]; r1 = r1 + zr[i+1]*zr[i+1];
        r2 = r2 + zr[i+2]*zr[i+2]; r3 = r3 + zr[i+3]*zr[i+3];
        r4 = r4 + zr[i+4]*zr[i+4]; r5 = r5 + zr[i+5]*zr[i+5];
        r6 = r6 + zr[i+6]*zr[i+6]; r7 = r7 + zr[i+7]*zr[i+7];
    }
    return ((r0 + r1) + (r2 + r3)) + ((r4 + r5) + (r6 + r7));
}

// ---------------- Kernel A: split-K argmin, hybrid LDS+SGPR operands --------
// grid = (GRIDX, NCHUNK); block = TPB.
__global__ __launch_bounds__(TPB, 3) void vq_argmin(const float* __restrict__ z,
                                                    const float* __restrict__ emb,
                                                    float* __restrict__ cmin,
                                                    int* __restrict__ cidx,
                                                    float* __restrict__ ws) {
#pragma clang fp contract(off)
    __shared__ float se[KCHUNK * CDIM];   // 32 KB
    __shared__ float sn[KCHUNK];

    const int chunk = blockIdx.y;
    const int k0 = chunk * KCHUNK;

    if ((blockIdx.x | blockIdx.y) == 0 && threadIdx.x == 0) {
        ws[OFF_LOSS] = 0.0f;                       // stream-ordered before finalize
        ((unsigned*)ws)[OFF_CTR] = 0u;             // graph-replay / re-poison safe
    }

    // stage this chunk's embedding rows (coalesced float4)
    const float4* esrc = (const float4*)(emb + (size_t)k0 * CDIM);
    float4* edst = (float4*)se;
    for (int i = threadIdx.x; i < KCHUNK * CDIM / 4; i += TPB) edst[i] = esrc[i];
    __syncthreads();
    // fused prep: ||e_k||^2 from the bit-exact staged copy (validated r12-r14).
    // Known cost: 32-way bank conflict here, ~2M cycles total (~3 µs). Accepted.
    if (threadIdx.x < KCHUNK) {
        const float* e = se + threadIdx.x * CDIM;
        float r0 = e[0]*e[0], r1 = e[1]*e[1], r2 = e[2]*e[2], r3 = e[3]*e[3];
        float r4 = e[4]*e[4], r5 = e[5]*e[5], r6 = e[6]*e[6], r7 = e[7]*e[7];
#pragma unroll
        for (int i = 8; i < CDIM; i += 8) {
            r0 = r0 + e[i+0]*e[i+0]; r1 = r1 + e[i+1]*e[i+1];
            r2 = r2 + e[i+2]*e[i+2]; r3 = r3 + e[i+3]*e[i+3];
            r4 = r4 + e[i+4]*e[i+4]; r5 = r5 + e[i+5]*e[i+5];
            r6 = r6 + e[i+6]*e[i+6]; r7 = r7 + e[i+7]*e[i+7];
        }
        sn[threadIdx.x] = ((r0 + r1) + (r2 + r3)) + ((r4 + r5) + (r6 + r7));
    }
    __syncthreads();

    // two pixels per thread, lane-coalesced; no tail (128*256*2 == N_PIX)
    const int p0 = blockIdx.x * (TPB * PXT) + threadIdx.x;
    const int p1 = p0 + TPB;

    float zr0[CDIM], zr1[CDIM];
    {
        const int b0  = p0 >> 12, hw0 = p0 & (HWSZ - 1);
        const int b1  = p1 >> 12, hw1 = p1 & (HWSZ - 1);
        const float* zp0 = z + ((size_t)(b0 * CDIM) << 12) + hw0;
        const float* zp1 = z + ((size_t)(b1 * CDIM) << 12) + hw1;
#pragma unroll
        for (int c = 0; c < CDIM; ++c) {
            zr0[c] = zp0[(size_t)c << 12];
            zr1[c] = zp1[(size_t)c << 12];
        }
    }
    const float nz0 = np_nz(zr0);
    const float nz1 = np_nz(zr1);

    float best0 = 3.4e38f, best1 = 3.4e38f;
    int   bi0   = k0,      bi1   = k0;

    for (int kk = 0; kk < KCHUNK; kk += 2) {
        // --- issue SGPR stream for code kk+1 (erow + 0x100..0x1c0) ---------
        const float* erow = emb + (size_t)(k0 + kk) * CDIM;
        f32x16 ec0, ec1, ec2, ec3;
        asm volatile(
            "s_load_dwordx16 %0, %4, 0x100\n\t"
            "s_load_dwordx16 %1, %4, 0x140\n\t"
            "s_load_dwordx16 %2, %4, 0x180\n\t"
            "s_load_dwordx16 %3, %4, 0x1c0"
            : "=s"(ec0), "=s"(ec1), "=s"(ec2), "=s"(ec3)
            : "s"(erow));

        // --- LDS phase: code kk for both pixels (r9's exact chains) --------
        const float4* e0 = (const float4*)(se + kk * CDIM);
        float a00 = 0.f, a01 = 0.f, a10 = 0.f, a11 = 0.f;
#pragma unroll
        for (int j = 0; j < 16; ++j) {
            float4 v0 = e0[j];                 // uniform addr -> LDS broadcast
            a00 = fmaf(zr0[4*j+0], v0.x, a00);
            a00 = fmaf(zr0[4*j+1], v0.y, a00);
            a00 = fmaf(zr0[4*j+2], v0.z, a00);
            a00 = fmaf(zr0[4*j+3], v0.w, a00);
            a10 = fmaf(zr1[4*j+0], v0.x, a10);
            a10 = fmaf(zr1[4*j+1], v0.y, a10);
            a10 = fmaf(zr1[4*j+2], v0.z, a10);
            a10 = fmaf(zr1[4*j+3], v0.w, a10);
        }

        // --- wait: pinned AFTER the LDS phase (produces a00,a10) and BEFORE
        //     the SGPR phase (consumes ec0..ec3 as this asm's outputs) -------
        asm volatile("s_waitcnt lgkmcnt(0)"
                     : "+s"(ec0), "+s"(ec1), "+s"(ec2), "+s"(ec3),
                       "+v"(a00), "+v"(a10));

        // --- SGPR phase: code kk+1 for both pixels (r15's exact chains) ----
#pragma unroll
        for (int j = 0; j < 16; ++j) {
            a01 = fmaf(zr0[j], ec0[j], a01);   // v_fma: VGPR,SGPR,VGPR
            a11 = fmaf(zr1[j], ec0[j], a11);
        }
#pragma unroll
        for (int j = 0; j < 16; ++j) {
            a01 = fmaf(zr0[16+j], ec1[j], a01);
            a11 = fmaf(zr1[16+j], ec1[j], a11);
        }
#pragma unroll
        for (int j = 0; j < 16; ++j) {
            a01 = fmaf(zr0[32+j], ec2[j], a01);
            a11 = fmaf(zr1[32+j], ec2[j], a11);
        }
#pragma unroll
        for (int j = 0; j < 16; ++j) {
            a01 = fmaf(zr0[48+j], ec3[j], a01);
            a11 = fmaf(zr1[48+j], ec3[j], a11);
        }

        // d and argmin — exact r9 expression shapes and update order
        float d00 = (nz0 - 2.0f * a00) + sn[kk];
        float d01 = (nz0 - 2.0f * a01) + sn[kk + 1];
        float d10 = (nz1 - 2.0f * a10) + sn[kk];
        float d11 = (nz1 - 2.0f * a11) + sn[kk + 1];
        if (d00 < best0) { best0 = d00; bi0 = k0 + kk; }
        if (d01 < best0) { best0 = d01; bi0 = k0 + kk + 1; }
        if (d10 < best1) { best1 = d10; bi1 = k0 + kk; }
        if (d11 < best1) { best1 = d11; bi1 = k0 + kk + 1; }
    }
    cmin[(p0 << 3) + chunk] = best0;
    cidx[(p0 << 3) + chunk] = bi0;
    cmin[(p1 << 3) + chunk] = best1;
    cidx[(p1 << 3) + chunk] = bi1;
}

// ---------------- Kernel B: reduce chunks, gather z_q, loss + emit ----------
__global__ __launch_bounds__(TPB) void vq_finalize(const float* __restrict__ z,
                                                   const float* __restrict__ emb,
                                                   const float* __restrict__ cmin,
                                                   const int* __restrict__ cidx,
                                                   float* __restrict__ out,
                                                   float* __restrict__ ws) {
    const int p = blockIdx.x * TPB + threadIdx.x;

    // ascending-chunk strict < keeps the earliest (lowest-k) minimum
    float best = cmin[p << 3];
    int   bi   = cidx[p << 3];
#pragma unroll
    for (int ch = 1; ch < NCHUNK; ++ch) {
        float m = cmin[(p << 3) + ch];
        if (m < best) { best = m; bi = cidx[(p << 3) + ch]; }
    }

    out[OUT_IDX + p] = (float)bi;       // indices output (fp32)

    const float* ev = emb + bi * CDIM;
    const int b  = p >> 12;
    const int hw = p & (HWSZ - 1);
    const float* zp = z + ((size_t)(b * CDIM) << 12) + hw;
    float* zq = out + ((size_t)(b * CDIM) << 12) + hw;

    float ls = 0.0f;
#pragma unroll
    for (int c = 0; c < CDIM; ++c) {
        float e = ev[c];                    // gather: rows hit L1/L2 (256KB table)
        float zv = zp[(size_t)c << 12];
        float d = e - zv;
        ls = fmaf(d, d, ls);
        zq[(size_t)c << 12] = e;            // fp32 z_q, coalesced strided store
    }

    // block reduction -> one atomic per block; last block scales + emits loss
#pragma unroll
    for (int off = 32; off > 0; off >>= 1) ls += __shfl_down(ls, off);
    __shared__ float wsum[TPB / 64];
    if ((threadIdx.x & 63) == 0) wsum[threadIdx.x >> 6] = ls;
    __syncthreads();
    if (threadIdx.x == 0) {
        float s = wsum[0] + wsum[1] + wsum[2] + wsum[3];
        float* loss_acc = ws + OFF_LOSS;
        atomicAdd(loss_acc, s);
        __threadfence();                               // add visible before count
        unsigned* ctr = (unsigned*)ws + OFF_CTR;
        unsigned old = atomicAdd(ctr, 1u);
        if (old == (unsigned)(gridDim.x - 1)) {        // last block: all adds done
            __threadfence();
            float total = atomicAdd(loss_acc, 0.0f);   // coherent L2 read
            // vq_loss + beta*commitment = (1+0.25) * SSE / numel(z)
            out[OUT_LOSS] = total * (1.25f / (float)(N_PIX * CDIM));
        }
    }
}

extern "C" void kernel_launch(void* const* d_in, const int* in_sizes, int n_in,
                              void* d_out, int out_size, void* d_ws, size_t ws_size,
                              hipStream_t stream) {
    const float* z   = (const float*)d_in[0];
    const float* emb = (const float*)d_in[1];
    float* ws   = (float*)d_ws;
    float* out  = (float*)d_out;
    float* cmin = ws + OFF_MIN;
    int*   cidx = (int*)(ws + OFF_IDX);

    vq_argmin<<<dim3(GRIDX, NCHUNK), dim3(TPB), 0, stream>>>(z, emb, cmin, cidx, ws);
    vq_finalize<<<dim3(N_PIX / TPB), dim3(TPB), 0, stream>>>(z, emb, cmin, cidx, out, ws);
}